// Round 2
// baseline (992.393 us; speedup 1.0000x reference)
//
#include <hip/hip_runtime.h>

// Fused spatial self-attention: B=4, C=512, N=4096 (single head, d=512).
// Pipeline: conv_w -> transpose(x->T bf16) -> proj<0> (Q,K,V^T) -> flash attn -> proj<1> (-> d_out fp32)
// All matmuls bf16-MFMA (16x16x32), fp32 accumulate.

#define B_ 4
#define C_ 512
#define N_ 4096

typedef unsigned short u16;
typedef __attribute__((ext_vector_type(8))) short bf16x8;
typedef __attribute__((ext_vector_type(4))) float f32x4;

#define MFMA16(a,b,c) __builtin_amdgcn_mfma_f32_16x16x32_bf16((a),(b),(c),0,0,0)

__device__ inline float exp2_fast(float x){
#if __has_builtin(__builtin_amdgcn_exp2f)
  return __builtin_amdgcn_exp2f(x);
#else
  return exp2f(x);
#endif
}

__device__ inline u16 f2bf(float f){
  unsigned u = __float_as_uint(f);
  u += 0x7FFFu + ((u >> 16) & 1u);   // RNE
  return (u16)(u >> 16);
}

// ---------------- weights fp32 -> bf16 ----------------
__global__ __launch_bounds__(256) void conv_w_kernel(const float* wq, const float* wk,
                                                     const float* wv, const float* wo, u16* out){
  int i = (blockIdx.x * 256 + threadIdx.x) * 8;      // grid 512 -> 1048576 elems
  int mat = i >> 18;                                 // /262144
  int within = i & 262143;
  const float* s = (mat==0) ? wq : (mat==1) ? wk : (mat==2) ? wv : wo;
  float4 a = *(const float4*)(s + within);
  float4 b = *(const float4*)(s + within + 4);
  unsigned u0 = f2bf(a.x) | ((unsigned)f2bf(a.y) << 16);
  unsigned u1 = f2bf(a.z) | ((unsigned)f2bf(a.w) << 16);
  unsigned u2 = f2bf(b.x) | ((unsigned)f2bf(b.y) << 16);
  unsigned u3 = f2bf(b.z) | ((unsigned)f2bf(b.w) << 16);
  uint4 v = {u0,u1,u2,u3};
  *(uint4*)(out + i) = v;
}

// ---------------- x (C,N) fp32 -> T (N,C) bf16 ----------------
__global__ __launch_bounds__(256) void transpose_kernel(const float* x, u16* T){
  __shared__ u16 tile[64][66];                       // +2 pad: conflict-light
  int b = blockIdx.z; int n0 = blockIdx.x*64; int c0 = blockIdx.y*64;
  int t = threadIdx.x;
  const float* xb = x + (size_t)b*C_*N_;
  int nn = t & 63, r0 = t >> 6;
  #pragma unroll
  for (int i=0;i<16;i++){
    int r = r0 + i*4;
    tile[r][nn] = f2bf(xb[(size_t)(c0+r)*N_ + n0 + nn]);
  }
  __syncthreads();
  int nrow = t >> 2, cs = t & 3;
  unsigned u[8];
  #pragma unroll
  for (int j=0;j<8;j++){
    u16 lo = tile[cs*16 + 2*j    ][nrow];
    u16 hi = tile[cs*16 + 2*j + 1][nrow];
    u[j] = lo | ((unsigned)hi << 16);
  }
  u16* dst = T + (size_t)b*N_*C_ + (size_t)(n0+nrow)*C_ + c0 + cs*16;
  uint4 v0 = {u[0],u[1],u[2],u[3]};
  uint4 v1 = {u[4],u[5],u[6],u[7]};
  *(uint4*)(dst)     = v0;
  *(uint4*)(dst + 8) = v1;
}

// ---------------- projection GEMM (NT, bf16 MFMA) ----------------
// out[n][co] = sum_k A[n][k] * W[co][k] + bias[co]
// MODE 0: z=(b,mat) q/k/v, bf16 out (V transposed); MODE 1: z=b, Wo, fp32 out.
template<int MODE>
__global__ __launch_bounds__(256) void proj_kernel(const u16* Abase, const u16* Wb,
                                                   const float* b0, const float* b1, const float* b2,
                                                   u16* Qo, u16* Ko, u16* VTo, float* Fo){
  __shared__ char lds[32768];
  char* Al = lds;            // [128 rows][128B] XOR-swizzled
  char* Bl = lds + 16384;    // [128 rows][128B] XOR-swizzled
  int z = blockIdx.z;
  int b, mat;
  if constexpr (MODE==0){ b = z/3; mat = z - b*3; } else { b = z; mat = 3; }
  const u16* A = Abase + (size_t)b*N_*C_;
  const u16* W = Wb + (size_t)mat*C_*C_;
  const float* bias = (MODE==0) ? (mat==0?b0:(mat==1?b1:b2)) : b0;
  int n0 = blockIdx.x*128, c0 = blockIdx.y*128;
  int t = threadIdx.x, lane = t & 63, w = t >> 6;
  int wm = w >> 1, wn = w & 1;
  int l15 = lane & 15, l4 = lane >> 4;
  f32x4 acc[4][4];
  #pragma unroll
  for (int i=0;i<4;i++)
    #pragma unroll
    for (int j=0;j<4;j++) acc[i][j] = f32x4{0.f,0.f,0.f,0.f};

  for (int ks=0; ks<8; ks++){
    int k0 = ks*64;
    __syncthreads();
    #pragma unroll
    for (int it=0; it<4; it++){
      int idx = it*256 + t, row = idx>>3, ch = idx&7;
      uint4 v = *(const uint4*)(A + (size_t)(n0+row)*C_ + k0 + ch*8);
      *(uint4*)(Al + row*128 + ((ch*16) ^ ((row&7)<<4))) = v;
    }
    #pragma unroll
    for (int it=0; it<4; it++){
      int idx = it*256 + t, row = idx>>3, ch = idx&7;
      uint4 v = *(const uint4*)(W + (size_t)(c0+row)*C_ + k0 + ch*8);
      *(uint4*)(Bl + row*128 + ((ch*16) ^ ((row&7)<<4))) = v;
    }
    __syncthreads();
    #pragma unroll
    for (int kk=0; kk<2; kk++){
      bf16x8 bfrag[4];
      #pragma unroll
      for (int ni=0; ni<4; ni++){
        int br = wn*64 + ni*16 + l15;
        bfrag[ni] = *(const bf16x8*)(Bl + br*128 + ((kk*64 + l4*16) ^ ((br&7)<<4)));
      }
      #pragma unroll
      for (int mi=0; mi<4; mi++){
        int ar = wm*64 + mi*16 + l15;
        bf16x8 afrag = *(const bf16x8*)(Al + ar*128 + ((kk*64 + l4*16) ^ ((ar&7)<<4)));
        #pragma unroll
        for (int ni=0; ni<4; ni++) acc[mi][ni] = MFMA16(afrag, bfrag[ni], acc[mi][ni]);
      }
    }
  }
  #pragma unroll
  for (int mi=0; mi<4; mi++){
    #pragma unroll
    for (int ni=0; ni<4; ni++){
      int col  = c0 + wn*64 + ni*16 + l15;
      int rowb = n0 + wm*64 + mi*16 + l4*4;
      float bb = bias[col];
      if constexpr (MODE==1){
        #pragma unroll
        for (int r=0;r<4;r++)
          Fo[(size_t)b*N_*C_ + (size_t)(rowb+r)*C_ + col] = acc[mi][ni][r] + bb;
      } else {
        if (mat==0){
          #pragma unroll
          for (int r=0;r<4;r++)
            Qo[(size_t)b*N_*C_ + (size_t)(rowb+r)*C_ + col] = f2bf(acc[mi][ni][r] + bb);
        } else if (mat==1){
          #pragma unroll
          for (int r=0;r<4;r++)
            Ko[(size_t)b*N_*C_ + (size_t)(rowb+r)*C_ + col] = f2bf(acc[mi][ni][r] + bb);
        } else {
          ushort4 pk;                                   // V stored transposed (C,N)
          pk.x = f2bf(acc[mi][ni][0] + bb);
          pk.y = f2bf(acc[mi][ni][1] + bb);
          pk.z = f2bf(acc[mi][ni][2] + bb);
          pk.w = f2bf(acc[mi][ni][3] + bb);
          *(ushort4*)(VTo + (size_t)b*(size_t)C_*N_ + (size_t)col*N_ + rowb) = pk;
        }
      }
    }
  }
}

// ---------------- flash attention ----------------
// Block: 4 waves x 16 q-rows (Q-tile 64). KV_BLK=64. Full-D (512) fp32 acc per wave.
// LDS: K[64][1024B] XOR-swizzled | V^T[512][144B pitch] | P[4][16][144B]
__global__ __launch_bounds__(256) void attn_kernel(const u16* Q, const u16* K, const u16* VT, u16* O){
  extern __shared__ char sm[];
  char* Kl = sm;                     // 65536
  char* Vl = sm + 65536;             // 73728
  char* Pl = sm + 65536 + 73728;     // 9216
  const float SC = (float)(1.4426950408889634 / 22.627416997969522); // log2(e)/sqrt(512)

  int t = threadIdx.x, lane = t & 63, w = t >> 6;
  int d = blockIdx.x;
  int L = (d & 7)*32 + (d >> 3);     // XCD swizzle: XCD x streams one half-batch
  int b = L >> 6, qt = L & 63;
  int n0 = qt*64 + w*16;
  int l15 = lane & 15, l4 = lane >> 4;

  // Q fragments resident in registers (16 rows x 512)
  bf16x8 qf[16];
  const u16* qp = Q + ((size_t)b*N_ + n0 + l15)*C_ + l4*8;
  #pragma unroll
  for (int kc=0;kc<16;kc++) qf[kc] = *(const bf16x8*)(qp + kc*32);

  f32x4 acc[32];
  #pragma unroll
  for (int i=0;i<32;i++) acc[i] = f32x4{0.f,0.f,0.f,0.f};
  float m[4], lsum[4];
  #pragma unroll
  for (int r=0;r<4;r++){ m[r] = -1e30f; lsum[r] = 0.f; }

  const char* Kg = (const char*)K  + (size_t)b*N_*C_*2;
  const char* Vg = (const char*)VT + (size_t)b*C_*N_*2;

  for (int s=0; s<64; s++){
    int kv0 = s*64;
    __syncthreads();                 // previous tile fully consumed
    // stage K (64 rows x 1024B), swizzled on write
    #pragma unroll 8
    for (int it=0; it<16; it++){
      int idx = it*256 + t, row = idx>>6, ch = idx&63;
      uint4 v = *(const uint4*)(Kg + (size_t)(kv0+row)*1024 + ch*16);
      *(uint4*)(Kl + row*1024 + ((ch*16) ^ ((row&7)<<4))) = v;
    }
    // stage V^T (512 rows x 128B -> pitch 144)
    #pragma unroll 8
    for (int it=0; it<16; it++){
      int idx = it*256 + t, crow = idx>>3, ch = idx&7;
      uint4 v = *(const uint4*)(Vg + (size_t)crow*8192 + (size_t)kv0*2 + ch*16);
      *(uint4*)(Vl + crow*144 + ch*16) = v;
    }
    __syncthreads();

    // scores: S[16 q][64 kv] over full D=512
    f32x4 sa[4];
    #pragma unroll
    for (int i=0;i<4;i++) sa[i] = f32x4{0.f,0.f,0.f,0.f};
    #pragma unroll
    for (int kc=0;kc<16;kc++){
      #pragma unroll
      for (int sub=0;sub<4;sub++){
        int kr = sub*16 + l15;
        bf16x8 kf = *(const bf16x8*)(Kl + kr*1024 + ((kc*64 + l4*16) ^ ((kr&7)<<4)));
        sa[sub] = MFMA16(qf[kc], kf, sa[sub]);
      }
    }

    // online softmax in log2-domain; lane owns rows l4*4+reg
    float uu[4][4], pmax[4];
    #pragma unroll
    for (int r=0;r<4;r++){
      float x0 = sa[0][r]*SC, x1 = sa[1][r]*SC, x2 = sa[2][r]*SC, x3 = sa[3][r]*SC;
      uu[0][r]=x0; uu[1][r]=x1; uu[2][r]=x2; uu[3][r]=x3;
      pmax[r] = fmaxf(fmaxf(x0,x1), fmaxf(x2,x3));
    }
    #pragma unroll
    for (int off=1; off<16; off<<=1){
      #pragma unroll
      for (int r=0;r<4;r++) pmax[r] = fmaxf(pmax[r], __shfl_xor(pmax[r], off));
    }
    bool need = false;
    #pragma unroll
    for (int r=0;r<4;r++) need = need || (pmax[r] > m[r] + 11.5f);  // defer-max (8 nats)
    if (__any(need)){
      float fac[4];
      #pragma unroll
      for (int r=0;r<4;r++){
        float mn = fmaxf(m[r], pmax[r]);
        fac[r] = exp2_fast(m[r]-mn);
        m[r] = mn; lsum[r] *= fac[r];
      }
      #pragma unroll
      for (int i=0;i<32;i++){
        #pragma unroll
        for (int r=0;r<4;r++) acc[i][r] *= fac[r];
      }
    }
    float rs[4] = {0.f,0.f,0.f,0.f};
    #pragma unroll
    for (int sub=0;sub<4;sub++){
      #pragma unroll
      for (int r=0;r<4;r++){
        float p = exp2_fast(uu[sub][r] - m[r]);
        rs[r] += p;
        *(u16*)(Pl + w*2304 + (l4*4+r)*144 + (sub*16+l15)*2) = f2bf(p);
      }
    }
    #pragma unroll
    for (int off=1; off<16; off<<=1){
      #pragma unroll
      for (int r=0;r<4;r++) rs[r] += __shfl_xor(rs[r], off);
    }
    #pragma unroll
    for (int r=0;r<4;r++) lsum[r] += rs[r];

    // P back as A-fragments (per-wave private LDS, no barrier needed)
    bf16x8 pa[2];
    #pragma unroll
    for (int k2=0;k2<2;k2++)
      pa[k2] = *(const bf16x8*)(Pl + w*2304 + l15*144 + k2*64 + l4*16);

    // PV: out[16 q][512 c] += P[16x64] * V[64 x 512]
    #pragma unroll
    for (int ci=0;ci<32;ci++){
      #pragma unroll
      for (int k2=0;k2<2;k2++){
        int cr = ci*16 + l15;
        bf16x8 vf = *(const bf16x8*)(Vl + cr*144 + k2*64 + l4*16);
        acc[ci] = MFMA16(pa[k2], vf, acc[ci]);
      }
    }
  }

  float rl[4];
  #pragma unroll
  for (int r=0;r<4;r++) rl[r] = 1.0f / lsum[r];
  u16* Ob = O + ((size_t)b*N_ + n0)*C_;
  #pragma unroll
  for (int ci=0;ci<32;ci++){
    #pragma unroll
    for (int r=0;r<4;r++)
      Ob[(size_t)(l4*4+r)*C_ + ci*16 + l15] = f2bf(acc[ci][r]*rl[r]);
  }
}

// ---------------- launch ----------------
extern "C" void kernel_launch(void* const* d_in, const int* in_sizes, int n_in,
                              void* d_out, int out_size, void* d_ws, size_t ws_size,
                              hipStream_t stream){
  const float* x  = (const float*)d_in[0];
  const float* Wq = (const float*)d_in[1];
  const float* bq = (const float*)d_in[2];
  const float* Wk = (const float*)d_in[3];
  const float* bk = (const float*)d_in[4];
  const float* Wv = (const float*)d_in[5];
  const float* bv = (const float*)d_in[6];
  const float* Wo = (const float*)d_in[7];
  const float* bo = (const float*)d_in[8];

  // ws layout (bytes): T/O 16MB | Wbf 2MB | Q 16MB | K 16MB | VT 16MB  (~66MB total)
  char* ws = (char*)d_ws;
  u16* Tb  = (u16*)(ws);               // T, later reused as attn output O
  u16* Wbf = (u16*)(ws + 16777216);
  u16* Qw  = (u16*)(ws + 18874368);
  u16* Kw  = (u16*)(ws + 35651584);
  u16* VTw = (u16*)(ws + 52428800);

  hipFuncSetAttribute((const void*)attn_kernel, hipFuncAttributeMaxDynamicSharedMemorySize, 148480);

  conv_w_kernel<<<512,256,0,stream>>>(Wq,Wk,Wv,Wo,Wbf);
  transpose_kernel<<<dim3(64,8,4),256,0,stream>>>(x, Tb);
  proj_kernel<0><<<dim3(32,4,12),256,0,stream>>>(Tb, Wbf, bq,bk,bv, Qw,Kw,VTw,nullptr);
  attn_kernel<<<dim3(256),256,148480,stream>>>(Qw,Kw,VTw,Tb);
  proj_kernel<1><<<dim3(32,4,4),256,0,stream>>>(Tb, Wbf, bo,nullptr,nullptr, nullptr,nullptr,nullptr,(float*)d_out);
}

// Round 4
// 627.606 us; speedup vs baseline: 1.5812x; 1.5812x over previous
//
#include <hip/hip_runtime.h>

// Fused spatial self-attention: B=4, C=512, N=4096 (single head, d=512).
// conv_w -> transpose(x->T bf16) -> proj<0> (Q,K,V^T) -> flash attn v2 -> proj<1> (-> d_out fp32)
// attn v2: 512 thr / 8 waves, q-tile 64. Waves 0-3: QK+softmax (16 rows each).
// All 8 waves: PV slab 64q x 64ch (M_rep=4,N_rep=4). All LDS XOR-swizzled.

#define B_ 4
#define C_ 512
#define N_ 4096

typedef unsigned short u16;
typedef __attribute__((ext_vector_type(8))) short bf16x8;
typedef __attribute__((ext_vector_type(4))) float f32x4;

#define MFMA16(a,b,c) __builtin_amdgcn_mfma_f32_16x16x32_bf16((a),(b),(c),0,0,0)

__device__ inline float exp2_fast(float x){
#if __has_builtin(__builtin_amdgcn_exp2f)
  return __builtin_amdgcn_exp2f(x);
#else
  return exp2f(x);
#endif
}

__device__ inline u16 f2bf(float f){
  unsigned u = __float_as_uint(f);
  u += 0x7FFFu + ((u >> 16) & 1u);   // RNE
  return (u16)(u >> 16);
}

// ---------------- weights fp32 -> bf16 ----------------
__global__ __launch_bounds__(256) void conv_w_kernel(const float* wq, const float* wk,
                                                     const float* wv, const float* wo, u16* out){
  int i = (blockIdx.x * 256 + threadIdx.x) * 8;
  int mat = i >> 18;
  int within = i & 262143;
  const float* s = (mat==0) ? wq : (mat==1) ? wk : (mat==2) ? wv : wo;
  float4 a = *(const float4*)(s + within);
  float4 b = *(const float4*)(s + within + 4);
  unsigned u0 = f2bf(a.x) | ((unsigned)f2bf(a.y) << 16);
  unsigned u1 = f2bf(a.z) | ((unsigned)f2bf(a.w) << 16);
  unsigned u2 = f2bf(b.x) | ((unsigned)f2bf(b.y) << 16);
  unsigned u3 = f2bf(b.z) | ((unsigned)f2bf(b.w) << 16);
  uint4 v = {u0,u1,u2,u3};
  *(uint4*)(out + i) = v;
}

// ---------------- x (C,N) fp32 -> T (N,C) bf16 ----------------
__global__ __launch_bounds__(256) void transpose_kernel(const float* x, u16* T){
  __shared__ u16 tile[64][66];
  int b = blockIdx.z; int n0 = blockIdx.x*64; int c0 = blockIdx.y*64;
  int t = threadIdx.x;
  const float* xb = x + (size_t)b*C_*N_;
  int nn = t & 63, r0 = t >> 6;
  #pragma unroll
  for (int i=0;i<16;i++){
    int r = r0 + i*4;
    tile[r][nn] = f2bf(xb[(size_t)(c0+r)*N_ + n0 + nn]);
  }
  __syncthreads();
  int nrow = t >> 2, cs = t & 3;
  unsigned u[8];
  #pragma unroll
  for (int j=0;j<8;j++){
    u16 lo = tile[cs*16 + 2*j    ][nrow];
    u16 hi = tile[cs*16 + 2*j + 1][nrow];
    u[j] = lo | ((unsigned)hi << 16);
  }
  u16* dst = T + (size_t)b*N_*C_ + (size_t)(n0+nrow)*C_ + c0 + cs*16;
  uint4 v0 = {u[0],u[1],u[2],u[3]};
  uint4 v1 = {u[4],u[5],u[6],u[7]};
  *(uint4*)(dst)     = v0;
  *(uint4*)(dst + 8) = v1;
}

// ---------------- projection GEMM (NT, bf16 MFMA) ----------------
template<int MODE>
__global__ __launch_bounds__(256) void proj_kernel(const u16* Abase, const u16* Wb,
                                                   const float* b0, const float* b1, const float* b2,
                                                   u16* Qo, u16* Ko, u16* VTo, float* Fo){
  __shared__ char lds[32768];
  char* Al = lds;
  char* Bl = lds + 16384;
  int z = blockIdx.z;
  int b, mat;
  if constexpr (MODE==0){ b = z/3; mat = z - b*3; } else { b = z; mat = 3; }
  const u16* A = Abase + (size_t)b*N_*C_;
  const u16* W = Wb + (size_t)mat*C_*C_;
  const float* bias = (MODE==0) ? (mat==0?b0:(mat==1?b1:b2)) : b0;
  int n0 = blockIdx.x*128, c0 = blockIdx.y*128;
  int t = threadIdx.x, lane = t & 63, w = t >> 6;
  int wm = w >> 1, wn = w & 1;
  int l15 = lane & 15, l4 = lane >> 4;
  f32x4 acc[4][4];
  #pragma unroll
  for (int i=0;i<4;i++)
    #pragma unroll
    for (int j=0;j<4;j++) acc[i][j] = f32x4{0.f,0.f,0.f,0.f};

  for (int ks=0; ks<8; ks++){
    int k0 = ks*64;
    __syncthreads();
    #pragma unroll
    for (int it=0; it<4; it++){
      int idx = it*256 + t, row = idx>>3, ch = idx&7;
      uint4 v = *(const uint4*)(A + (size_t)(n0+row)*C_ + k0 + ch*8);
      *(uint4*)(Al + row*128 + ((ch*16) ^ ((row&7)<<4))) = v;
    }
    #pragma unroll
    for (int it=0; it<4; it++){
      int idx = it*256 + t, row = idx>>3, ch = idx&7;
      uint4 v = *(const uint4*)(W + (size_t)(c0+row)*C_ + k0 + ch*8);
      *(uint4*)(Bl + row*128 + ((ch*16) ^ ((row&7)<<4))) = v;
    }
    __syncthreads();
    #pragma unroll
    for (int kk=0; kk<2; kk++){
      bf16x8 bfrag[4];
      #pragma unroll
      for (int ni=0; ni<4; ni++){
        int br = wn*64 + ni*16 + l15;
        bfrag[ni] = *(const bf16x8*)(Bl + br*128 + ((kk*64 + l4*16) ^ ((br&7)<<4)));
      }
      #pragma unroll
      for (int mi=0; mi<4; mi++){
        int ar = wm*64 + mi*16 + l15;
        bf16x8 afrag = *(const bf16x8*)(Al + ar*128 + ((kk*64 + l4*16) ^ ((ar&7)<<4)));
        #pragma unroll
        for (int ni=0; ni<4; ni++) acc[mi][ni] = MFMA16(afrag, bfrag[ni], acc[mi][ni]);
      }
    }
  }
  #pragma unroll
  for (int mi=0; mi<4; mi++){
    #pragma unroll
    for (int ni=0; ni<4; ni++){
      int col  = c0 + wn*64 + ni*16 + l15;
      int rowb = n0 + wm*64 + mi*16 + l4*4;
      float bb = bias[col];
      if constexpr (MODE==1){
        #pragma unroll
        for (int r=0;r<4;r++)
          Fo[(size_t)b*N_*C_ + (size_t)(rowb+r)*C_ + col] = acc[mi][ni][r] + bb;
      } else {
        if (mat==0){
          #pragma unroll
          for (int r=0;r<4;r++)
            Qo[(size_t)b*N_*C_ + (size_t)(rowb+r)*C_ + col] = f2bf(acc[mi][ni][r] + bb);
        } else if (mat==1){
          #pragma unroll
          for (int r=0;r<4;r++)
            Ko[(size_t)b*N_*C_ + (size_t)(rowb+r)*C_ + col] = f2bf(acc[mi][ni][r] + bb);
        } else {
          ushort4 pk;                                   // V stored transposed (C,N)
          pk.x = f2bf(acc[mi][ni][0] + bb);
          pk.y = f2bf(acc[mi][ni][1] + bb);
          pk.z = f2bf(acc[mi][ni][2] + bb);
          pk.w = f2bf(acc[mi][ni][3] + bb);
          *(ushort4*)(VTo + (size_t)b*(size_t)C_*N_ + (size_t)col*N_ + rowb) = pk;
        }
      }
    }
  }
}

// ---------------- flash attention v2 ----------------
// 512 thr / 8 waves. Q-tile 64 rows. KV_BLK=64, 64 steps.
// LDS: K[64][1024B] swz | V^T[512][128B] swz | P[64][128B] swz | fac[64] f32 | lrow[64] f32
// Waves 0-3: QK (16 rows each) + softmax + P/fac write. All 8: PV slab 64q x 64ch.
// __launch_bounds__(512,2): 8 waves resident requires <=256 VGPR/wave.
__global__ __launch_bounds__(512, 2) void attn_kernel(const u16* Q, const u16* K, const u16* VT, u16* O){
  extern __shared__ char sm[];
  char* Kl = sm;                       // 65536
  char* Vl = sm + 65536;               // 65536
  char* Pl = sm + 131072;              // 8192
  float* fac  = (float*)(sm + 139264); // 64
  float* lrow = (float*)(sm + 139520); // 64
  const float SC = (float)(1.4426950408889634 / 22.627416997969522); // log2(e)/sqrt(512)

  int t = threadIdx.x, lane = t & 63, w = t >> 6;
  int l15 = lane & 15, l4 = lane >> 4;
  int d = blockIdx.x;
  int L = (d & 7)*32 + (d >> 3);       // XCD swizzle: each XCD streams one batch's K/V
  int b = L >> 6, qt = L & 63;
  int n0 = qt*64;

  // Q resident (waves 0-3 only): wave w owns q-rows n0+16w .. +15
  bf16x8 qf[16];
  if (w < 4){
    const u16* qp = Q + ((size_t)b*N_ + n0 + 16*w + l15)*C_ + l4*8;
    #pragma unroll
    for (int kc=0;kc<16;kc++) qf[kc] = *(const bf16x8*)(qp + kc*32);
  }

  f32x4 acc[4][4];                     // slab: rows mi*16+l4*4+r, cols w*64+ni*16+l15
  #pragma unroll
  for (int i=0;i<4;i++)
    #pragma unroll
    for (int j=0;j<4;j++) acc[i][j] = f32x4{0.f,0.f,0.f,0.f};
  float m[4], lsum[4];
  #pragma unroll
  for (int r=0;r<4;r++){ m[r] = -1e30f; lsum[r] = 0.f; }

  const char* Kg = (const char*)K  + (size_t)b*N_*C_*2;
  const char* Vg = (const char*)VT + (size_t)b*C_*N_*2;

  for (int s=0; s<64; s++){
    int kv0 = s*64;
    __syncthreads();                   // prev tile fully consumed
    // stage K: 64 rows x 1024B (issue all 8 loads, then write)
    {
      uint4 tmp[8];
      #pragma unroll
      for (int it=0; it<8; it++){
        int idx = it*512 + t, row = idx>>6, ch = idx&63;
        tmp[it] = *(const uint4*)(Kg + (size_t)(kv0+row)*1024 + ch*16);
      }
      #pragma unroll
      for (int it=0; it<8; it++){
        int idx = it*512 + t, row = idx>>6, ch = idx&63;
        *(uint4*)(Kl + row*1024 + ((ch*16) ^ ((row&7)<<4))) = tmp[it];
      }
    }
    // stage V^T: 512 rows x 128B
    {
      uint4 tmp[8];
      #pragma unroll
      for (int it=0; it<8; it++){
        int idx = it*512 + t, crow = idx>>3, ch = idx&7;
        tmp[it] = *(const uint4*)(Vg + (size_t)crow*8192 + (size_t)kv0*2 + ch*16);
      }
      #pragma unroll
      for (int it=0; it<8; it++){
        int idx = it*512 + t, crow = idx>>3, ch = idx&7;
        *(uint4*)(Vl + crow*128 + ((ch*16) ^ ((crow&7)<<4))) = tmp[it];
      }
    }
    __syncthreads();

    if (w < 4){
      // QK: S[16 q][64 kv] over D=512
      f32x4 sa[4];
      #pragma unroll
      for (int i=0;i<4;i++) sa[i] = f32x4{0.f,0.f,0.f,0.f};
      #pragma unroll
      for (int kc=0;kc<16;kc++){
        #pragma unroll
        for (int sub=0;sub<4;sub++){
          int kr = sub*16 + l15;
          bf16x8 kf = *(const bf16x8*)(Kl + kr*1024 + ((kc*64 + l4*16) ^ ((kr&7)<<4)));
          sa[sub] = MFMA16(qf[kc], kf, sa[sub]);
        }
      }
      // online softmax (log2 domain); lane owns rows 16w + l4*4 + r
      float uu[4][4], pmax[4];
      #pragma unroll
      for (int r=0;r<4;r++){
        float x0 = sa[0][r]*SC, x1 = sa[1][r]*SC, x2 = sa[2][r]*SC, x3 = sa[3][r]*SC;
        uu[0][r]=x0; uu[1][r]=x1; uu[2][r]=x2; uu[3][r]=x3;
        pmax[r] = fmaxf(fmaxf(x0,x1), fmaxf(x2,x3));
      }
      #pragma unroll
      for (int off=1; off<16; off<<=1){
        #pragma unroll
        for (int r=0;r<4;r++) pmax[r] = fmaxf(pmax[r], __shfl_xor(pmax[r], off));
      }
      bool need = false;
      #pragma unroll
      for (int r=0;r<4;r++) need = need || (pmax[r] > m[r] + 11.5f);  // defer-max
      float fv[4];
      if (__any(need)){
        #pragma unroll
        for (int r=0;r<4;r++){
          float mn = fmaxf(m[r], pmax[r]);
          fv[r] = exp2_fast(m[r]-mn);
          m[r] = mn; lsum[r] *= fv[r];
        }
      } else {
        #pragma unroll
        for (int r=0;r<4;r++) fv[r] = 1.0f;
      }
      if (l15 == 0){
        #pragma unroll
        for (int r=0;r<4;r++) fac[16*w + l4*4 + r] = fv[r];
      }
      float rs[4] = {0.f,0.f,0.f,0.f};
      #pragma unroll
      for (int sub=0;sub<4;sub++){
        #pragma unroll
        for (int r=0;r<4;r++){
          float p = exp2_fast(uu[sub][r] - m[r]);
          rs[r] += p;
          int row = 16*w + l4*4 + r, col = sub*16 + l15;
          *(u16*)(Pl + row*128 + ((col*2) ^ ((row&7)<<4))) = f2bf(p);
        }
      }
      #pragma unroll
      for (int off=1; off<16; off<<=1){
        #pragma unroll
        for (int r=0;r<4;r++) rs[r] += __shfl_xor(rs[r], off);
      }
      #pragma unroll
      for (int r=0;r<4;r++) lsum[r] += rs[r];
    }
    __syncthreads();                   // P + fac visible

    // all 8 waves: unconditional rescale (fac==1.0 when no rescale), then PV
    f32x4 facv[4];
    #pragma unroll
    for (int mi=0;mi<4;mi++) facv[mi] = *(const f32x4*)(fac + mi*16 + l4*4);
    #pragma unroll
    for (int mi=0;mi<4;mi++)
      #pragma unroll
      for (int ni=0;ni<4;ni++)
        #pragma unroll
        for (int r=0;r<4;r++) acc[mi][ni][r] *= facv[mi][r];

    bf16x8 vf[4][2];
    #pragma unroll
    for (int ni=0;ni<4;ni++)
      #pragma unroll
      for (int kk=0;kk<2;kk++){
        int crow = w*64 + ni*16 + l15;
        vf[ni][kk] = *(const bf16x8*)(Vl + crow*128 + ((kk*64 + l4*16) ^ ((crow&7)<<4)));
      }
    #pragma unroll
    for (int mi=0;mi<4;mi++){
      bf16x8 pa[2];
      #pragma unroll
      for (int kk=0;kk<2;kk++){
        int row = mi*16 + l15;
        pa[kk] = *(const bf16x8*)(Pl + row*128 + ((kk*64 + l4*16) ^ ((row&7)<<4)));
      }
      #pragma unroll
      for (int ni=0;ni<4;ni++){
        acc[mi][ni] = MFMA16(pa[0], vf[ni][0], acc[mi][ni]);
        acc[mi][ni] = MFMA16(pa[1], vf[ni][1], acc[mi][ni]);
      }
    }
  }

  // final: owners publish row sums, everyone normalizes their slab
  if (w < 4 && l15 == 0){
    #pragma unroll
    for (int r=0;r<4;r++) lrow[16*w + l4*4 + r] = lsum[r];
  }
  __syncthreads();
  u16* Ob = O + ((size_t)b*N_ + n0)*C_;
  #pragma unroll
  for (int mi=0;mi<4;mi++){
    f32x4 lv = *(const f32x4*)(lrow + mi*16 + l4*4);
    f32x4 rl;
    #pragma unroll
    for (int r=0;r<4;r++) rl[r] = 1.0f / lv[r];
    #pragma unroll
    for (int ni=0;ni<4;ni++){
      #pragma unroll
      for (int r=0;r<4;r++){
        int row = mi*16 + l4*4 + r, col = w*64 + ni*16 + l15;
        Ob[(size_t)row*C_ + col] = f2bf(acc[mi][ni][r]*rl[r]);
      }
    }
  }
}

// ---------------- launch ----------------
extern "C" void kernel_launch(void* const* d_in, const int* in_sizes, int n_in,
                              void* d_out, int out_size, void* d_ws, size_t ws_size,
                              hipStream_t stream){
  const float* x  = (const float*)d_in[0];
  const float* Wq = (const float*)d_in[1];
  const float* bq = (const float*)d_in[2];
  const float* Wk = (const float*)d_in[3];
  const float* bk = (const float*)d_in[4];
  const float* Wv = (const float*)d_in[5];
  const float* bv = (const float*)d_in[6];
  const float* Wo = (const float*)d_in[7];
  const float* bo = (const float*)d_in[8];

  char* ws = (char*)d_ws;
  u16* Tb  = (u16*)(ws);               // T, later reused as attn output O
  u16* Wbf = (u16*)(ws + 16777216);
  u16* Qw  = (u16*)(ws + 18874368);
  u16* Kw  = (u16*)(ws + 35651584);
  u16* VTw = (u16*)(ws + 52428800);

  hipFuncSetAttribute((const void*)attn_kernel, hipFuncAttributeMaxDynamicSharedMemorySize, 139776);

  conv_w_kernel<<<512,256,0,stream>>>(Wq,Wk,Wv,Wo,Wbf);
  transpose_kernel<<<dim3(64,8,4),256,0,stream>>>(x, Tb);
  proj_kernel<0><<<dim3(32,4,12),256,0,stream>>>(Tb, Wbf, bq,bk,bv, Qw,Kw,VTw,nullptr);
  attn_kernel<<<dim3(256),512,139776,stream>>>(Qw,Kw,VTw,Tb);
  proj_kernel<1><<<dim3(32,4,4),256,0,stream>>>(Tb, Wbf, bo,nullptr,nullptr, nullptr,nullptr,nullptr,(float*)d_out);
}

// Round 7
// 444.331 us; speedup vs baseline: 2.2335x; 1.4125x over previous
//
#include <hip/hip_runtime.h>

// Fused spatial self-attention: B=4, C=512, N=4096 (single head, d=512).
// conv_w -> transpose(x->T bf16) -> proj<0> (Q,K,V^T) -> flash attn v3 -> proj<1> (-> d_out fp32)
// attn v3: 512 thr / 8 waves, q-tile 64, KVBLK=32, double-buffered K/V via
// global_load_lds DMA (pre-swizzled global source, linear LDS dest),
// amdgpu_waves_per_eu(2,2) so qf[16] stays register-resident (v2 remat bug).

#define B_ 4
#define C_ 512
#define N_ 4096
#define KV_ 32
#define NSTEP 128

typedef unsigned short u16;
typedef __attribute__((ext_vector_type(8))) short bf16x8;
typedef __attribute__((ext_vector_type(4))) float f32x4;

#define MFMA16(a,b,c) __builtin_amdgcn_mfma_f32_16x16x32_bf16((a),(b),(c),0,0,0)

__device__ inline float exp2_fast(float x){
#if __has_builtin(__builtin_amdgcn_exp2f)
  return __builtin_amdgcn_exp2f(x);
#else
  return exp2f(x);
#endif
}

__device__ inline u16 f2bf(float f){
  unsigned u = __float_as_uint(f);
  u += 0x7FFFu + ((u >> 16) & 1u);   // RNE
  return (u16)(u >> 16);
}

// async global->LDS DMA, 16B per lane. HW writes lane i at ldsbase + i*16.
// Caller passes WAVE-UNIFORM lds base and PER-LANE global src (pre-swizzled).
__device__ __forceinline__ void gload16(const char* g, char* l){
#if __has_builtin(__builtin_amdgcn_global_load_lds)
  __builtin_amdgcn_global_load_lds(
      (const __attribute__((address_space(1))) unsigned int*)(unsigned long long)g,
      (__attribute__((address_space(3))) unsigned int*)(unsigned int)(unsigned long long)l,
      16, 0, 0);
#else
  int lane = threadIdx.x & 63;
  *(uint4*)(l + lane*16) = *(const uint4*)g;
#endif
}

// ---------------- weights fp32 -> bf16 ----------------
__global__ __launch_bounds__(256) void conv_w_kernel(const float* wq, const float* wk,
                                                     const float* wv, const float* wo, u16* out){
  int i = (blockIdx.x * 256 + threadIdx.x) * 8;
  int mat = i >> 18;
  int within = i & 262143;
  const float* s = (mat==0) ? wq : (mat==1) ? wk : (mat==2) ? wv : wo;
  float4 a = *(const float4*)(s + within);
  float4 b = *(const float4*)(s + within + 4);
  unsigned u0 = f2bf(a.x) | ((unsigned)f2bf(a.y) << 16);
  unsigned u1 = f2bf(a.z) | ((unsigned)f2bf(a.w) << 16);
  unsigned u2 = f2bf(b.x) | ((unsigned)f2bf(b.y) << 16);
  unsigned u3 = f2bf(b.z) | ((unsigned)f2bf(b.w) << 16);
  uint4 v = {u0,u1,u2,u3};
  *(uint4*)(out + i) = v;
}

// ---------------- x (C,N) fp32 -> T (N,C) bf16 ----------------
__global__ __launch_bounds__(256) void transpose_kernel(const float* x, u16* T){
  __shared__ u16 tile[64][66];
  int b = blockIdx.z; int n0 = blockIdx.x*64; int c0 = blockIdx.y*64;
  int t = threadIdx.x;
  const float* xb = x + (size_t)b*C_*N_;
  int nn = t & 63, r0 = t >> 6;
  #pragma unroll
  for (int i=0;i<16;i++){
    int r = r0 + i*4;
    tile[r][nn] = f2bf(xb[(size_t)(c0+r)*N_ + n0 + nn]);
  }
  __syncthreads();
  int nrow = t >> 2, cs = t & 3;
  unsigned u[8];
  #pragma unroll
  for (int j=0;j<8;j++){
    u16 lo = tile[cs*16 + 2*j    ][nrow];
    u16 hi = tile[cs*16 + 2*j + 1][nrow];
    u[j] = lo | ((unsigned)hi << 16);
  }
  u16* dst = T + (size_t)b*N_*C_ + (size_t)(n0+nrow)*C_ + c0 + cs*16;
  uint4 v0 = {u[0],u[1],u[2],u[3]};
  uint4 v1 = {u[4],u[5],u[6],u[7]};
  *(uint4*)(dst)     = v0;
  *(uint4*)(dst + 8) = v1;
}

// ---------------- projection GEMM (NT, bf16 MFMA) ----------------
template<int MODE>
__global__ __launch_bounds__(256) void proj_kernel(const u16* Abase, const u16* Wb,
                                                   const float* b0, const float* b1, const float* b2,
                                                   u16* Qo, u16* Ko, u16* VTo, float* Fo){
  __shared__ char lds[32768];
  char* Al = lds;
  char* Bl = lds + 16384;
  int z = blockIdx.z;
  int b, mat;
  if constexpr (MODE==0){ b = z/3; mat = z - b*3; } else { b = z; mat = 3; }
  const u16* A = Abase + (size_t)b*N_*C_;
  const u16* W = Wb + (size_t)mat*C_*C_;
  const float* bias = (MODE==0) ? (mat==0?b0:(mat==1?b1:b2)) : b0;
  int n0 = blockIdx.x*128, c0 = blockIdx.y*128;
  int t = threadIdx.x, lane = t & 63, w = t >> 6;
  int wm = w >> 1, wn = w & 1;
  int l15 = lane & 15, l4 = lane >> 4;
  f32x4 acc[4][4];
  #pragma unroll
  for (int i=0;i<4;i++)
    #pragma unroll
    for (int j=0;j<4;j++) acc[i][j] = f32x4{0.f,0.f,0.f,0.f};

  for (int ks=0; ks<8; ks++){
    int k0 = ks*64;
    __syncthreads();
    #pragma unroll
    for (int it=0; it<4; it++){
      int idx = it*256 + t, row = idx>>3, ch = idx&7;
      uint4 v = *(const uint4*)(A + (size_t)(n0+row)*C_ + k0 + ch*8);
      *(uint4*)(Al + row*128 + ((ch*16) ^ ((row&7)<<4))) = v;
    }
    #pragma unroll
    for (int it=0; it<4; it++){
      int idx = it*256 + t, row = idx>>3, ch = idx&7;
      uint4 v = *(const uint4*)(W + (size_t)(c0+row)*C_ + k0 + ch*8);
      *(uint4*)(Bl + row*128 + ((ch*16) ^ ((row&7)<<4))) = v;
    }
    __syncthreads();
    #pragma unroll
    for (int kk=0; kk<2; kk++){
      bf16x8 bfrag[4];
      #pragma unroll
      for (int ni=0; ni<4; ni++){
        int br = wn*64 + ni*16 + l15;
        bfrag[ni] = *(const bf16x8*)(Bl + br*128 + ((kk*64 + l4*16) ^ ((br&7)<<4)));
      }
      #pragma unroll
      for (int mi=0; mi<4; mi++){
        int ar = wm*64 + mi*16 + l15;
        bf16x8 afrag = *(const bf16x8*)(Al + ar*128 + ((kk*64 + l4*16) ^ ((ar&7)<<4)));
        #pragma unroll
        for (int ni=0; ni<4; ni++) acc[mi][ni] = MFMA16(afrag, bfrag[ni], acc[mi][ni]);
      }
    }
  }
  #pragma unroll
  for (int mi=0; mi<4; mi++){
    #pragma unroll
    for (int ni=0; ni<4; ni++){
      int col  = c0 + wn*64 + ni*16 + l15;
      int rowb = n0 + wm*64 + mi*16 + l4*4;
      float bb = bias[col];
      if constexpr (MODE==1){
        #pragma unroll
        for (int r=0;r<4;r++)
          Fo[(size_t)b*N_*C_ + (size_t)(rowb+r)*C_ + col] = acc[mi][ni][r] + bb;
      } else {
        if (mat==0){
          #pragma unroll
          for (int r=0;r<4;r++)
            Qo[(size_t)b*N_*C_ + (size_t)(rowb+r)*C_ + col] = f2bf(acc[mi][ni][r] + bb);
        } else if (mat==1){
          #pragma unroll
          for (int r=0;r<4;r++)
            Ko[(size_t)b*N_*C_ + (size_t)(rowb+r)*C_ + col] = f2bf(acc[mi][ni][r] + bb);
        } else {
          ushort4 pk;                                   // V stored transposed (C,N)
          pk.x = f2bf(acc[mi][ni][0] + bb);
          pk.y = f2bf(acc[mi][ni][1] + bb);
          pk.z = f2bf(acc[mi][ni][2] + bb);
          pk.w = f2bf(acc[mi][ni][3] + bb);
          *(ushort4*)(VTo + (size_t)b*(size_t)C_*N_ + (size_t)col*N_ + rowb) = pk;
        }
      }
    }
  }
}

// ---------------- flash attention v3 ----------------
// 512 thr / 8 waves. Q-tile 64, KVBLK=32, 128 steps, double-buffered DMA staging.
// LDS: K2[2][32KB] | V2[2][32KB] | P[64][64B] | fac[64] | lrow[64]  = 132.5 KB
// K row: 1024B, XOR swz (row&7)<<4 (pre-applied at global src).
// V^T row (=channel): 64B, XOR swz (row&3)<<4 (pre-applied at global src).
__global__ __launch_bounds__(512) __attribute__((amdgpu_waves_per_eu(2, 2)))
void attn_kernel(const u16* Q, const u16* K, const u16* VT, u16* O){
  extern __shared__ char sm[];
  char* Pl   = sm + 131072;            // 4096
  float* fac  = (float*)(sm + 135168); // 64
  float* lrow = (float*)(sm + 135424); // 64
  const float SC = (float)(1.4426950408889634 / 22.627416997969522); // log2(e)/sqrt(512)

  int t = threadIdx.x, lane = t & 63, w = t >> 6;
  int l15 = lane & 15, l4 = lane >> 4;
  int d = blockIdx.x;
  int L = (d & 7)*32 + (d >> 3);       // XCD swizzle
  int b = L >> 6, qt = L & 63;
  int n0 = qt*64;

  const char* Kg = (const char*)K  + (size_t)b*N_*C_*2;
  const char* Vg = (const char*)VT + (size_t)b*C_*N_*2;

  // stage step `step` into buffer `sel` (8 DMA calls per wave, no VGPR round-trip)
  auto stage = [&](int step, int sel){
    int kv0 = step*KV_;
    char* Kn = sm + sel*32768;
    char* Vn = sm + 65536 + sel*32768;
    #pragma unroll
    for (int i=0;i<4;i++){
      int row = w*4 + i;
      gload16(Kg + (size_t)(kv0+row)*1024 + ((lane*16) ^ ((row&7)<<4)), Kn + row*1024);
    }
    int rr = lane >> 2, bb = (lane & 3)*16;
    #pragma unroll
    for (int i=0;i<4;i++){
      int c = w*4 + i;
      gload16(Vg + (size_t)(c*16+rr)*8192 + (size_t)kv0*2 + (bb ^ ((rr&3)<<4)), Vn + c*1024);
    }
  };

  // Q resident in registers (waves 0-3): wave w owns q-rows n0+16w..+15
  bf16x8 qf[16];
  if (w < 4){
    const u16* qp = Q + ((size_t)b*N_ + n0 + 16*w + l15)*C_ + l4*8;
    #pragma unroll
    for (int kc=0;kc<16;kc++) qf[kc] = *(const bf16x8*)(qp + kc*32);
  }

  f32x4 acc[4][4];                     // rows mi*16+l4*4+r, cols w*64+ni*16+l15
  #pragma unroll
  for (int i=0;i<4;i++)
    #pragma unroll
    for (int j=0;j<4;j++) acc[i][j] = f32x4{0.f,0.f,0.f,0.f};
  float m[4], lsum[4];
  #pragma unroll
  for (int r=0;r<4;r++){ m[r] = -1e30f; lsum[r] = 0.f; }

  stage(0, 0);
  __syncthreads();                     // drains vmcnt -> buf0 ready

  for (int s=0; s<NSTEP; s++){
    char* Kc = sm + (s&1)*32768;
    char* Vc = sm + 65536 + (s&1)*32768;
    if (s+1 < NSTEP) stage(s+1, (s+1)&1);   // DMA into inactive buffer

    if (w < 4){
      // QK: S[16 q][32 kv] over D=512
      f32x4 sa[2];
      sa[0] = f32x4{0.f,0.f,0.f,0.f}; sa[1] = f32x4{0.f,0.f,0.f,0.f};
      #pragma unroll
      for (int kc=0;kc<16;kc++){
        #pragma unroll
        for (int sub=0;sub<2;sub++){
          int kr = sub*16 + l15;
          bf16x8 kf = *(const bf16x8*)(Kc + kr*1024 + ((kc*64 + l4*16) ^ ((kr&7)<<4)));
          sa[sub] = MFMA16(qf[kc], kf, sa[sub]);
        }
      }
      // online softmax (log2 domain); lane owns rows 16w + l4*4 + r
      float uu[2][4], pmax[4];
      #pragma unroll
      for (int r=0;r<4;r++){
        float x0 = sa[0][r]*SC, x1 = sa[1][r]*SC;
        uu[0][r]=x0; uu[1][r]=x1;
        pmax[r] = fmaxf(x0,x1);
      }
      #pragma unroll
      for (int off=1; off<16; off<<=1){
        #pragma unroll
        for (int r=0;r<4;r++) pmax[r] = fmaxf(pmax[r], __shfl_xor(pmax[r], off));
      }
      bool need = false;
      #pragma unroll
      for (int r=0;r<4;r++) need = need || (pmax[r] > m[r] + 11.5f);  // defer-max
      float fv[4];
      if (__any(need)){
        #pragma unroll
        for (int r=0;r<4;r++){
          float mn = fmaxf(m[r], pmax[r]);
          fv[r] = exp2_fast(m[r]-mn);
          m[r] = mn; lsum[r] *= fv[r];
        }
      } else {
        #pragma unroll
        for (int r=0;r<4;r++) fv[r] = 1.0f;
      }
      if (l15 == 0){
        #pragma unroll
        for (int r=0;r<4;r++) fac[16*w + l4*4 + r] = fv[r];
      }
      float rs[4] = {0.f,0.f,0.f,0.f};
      #pragma unroll
      for (int sub=0;sub<2;sub++){
        #pragma unroll
        for (int r=0;r<4;r++){
          float p = exp2_fast(uu[sub][r] - m[r]);
          rs[r] += p;
          int row = 16*w + l4*4 + r, col = sub*16 + l15;
          *(u16*)(Pl + row*64 + ((col*2) ^ ((row&3)<<4))) = f2bf(p);
        }
      }
      #pragma unroll
      for (int off=1; off<16; off<<=1){
        #pragma unroll
        for (int r=0;r<4;r++) rs[r] += __shfl_xor(rs[r], off);
      }
      #pragma unroll
      for (int r=0;r<4;r++) lsum[r] += rs[r];
    }
    __syncthreads();                   // P + fac visible

    // all 8 waves: unconditional rescale, then PV (KV-depth 32 = one MFMA)
    f32x4 facv[4];
    #pragma unroll
    for (int mi=0;mi<4;mi++) facv[mi] = *(const f32x4*)(fac + mi*16 + l4*4);
    #pragma unroll
    for (int mi=0;mi<4;mi++)
      #pragma unroll
      for (int ni=0;ni<4;ni++)
        #pragma unroll
        for (int r=0;r<4;r++) acc[mi][ni][r] *= facv[mi][r];

    bf16x8 vf[4];
    #pragma unroll
    for (int ni=0;ni<4;ni++){
      int crow = w*64 + ni*16 + l15;
      vf[ni] = *(const bf16x8*)(Vc + crow*64 + ((l4*16) ^ ((crow&3)<<4)));
    }
    #pragma unroll
    for (int mi=0;mi<4;mi++){
      int prow = mi*16 + l15;
      bf16x8 pa = *(const bf16x8*)(Pl + prow*64 + ((l4*16) ^ ((prow&3)<<4)));
      #pragma unroll
      for (int ni=0;ni<4;ni++) acc[mi][ni] = MFMA16(pa, vf[ni], acc[mi][ni]);
    }
    __syncthreads();                   // buf[s&1] consumed; drains next-tile DMA
  }

  // final: owners publish row sums, everyone normalizes their slab
  if (w < 4 && l15 == 0){
    #pragma unroll
    for (int r=0;r<4;r++) lrow[16*w + l4*4 + r] = lsum[r];
  }
  __syncthreads();
  u16* Ob = O + ((size_t)b*N_ + n0)*C_;
  #pragma unroll
  for (int mi=0;mi<4;mi++){
    f32x4 lv = *(const f32x4*)(lrow + mi*16 + l4*4);
    f32x4 rl;
    #pragma unroll
    for (int r=0;r<4;r++) rl[r] = 1.0f / lv[r];
    #pragma unroll
    for (int ni=0;ni<4;ni++){
      #pragma unroll
      for (int r=0;r<4;r++){
        int row = mi*16 + l4*4 + r, col = w*64 + ni*16 + l15;
        Ob[(size_t)row*C_ + col] = f2bf(acc[mi][ni][r]*rl[r]);
      }
    }
  }
}

// ---------------- launch ----------------
extern "C" void kernel_launch(void* const* d_in, const int* in_sizes, int n_in,
                              void* d_out, int out_size, void* d_ws, size_t ws_size,
                              hipStream_t stream){
  const float* x  = (const float*)d_in[0];
  const float* Wq = (const float*)d_in[1];
  const float* bq = (const float*)d_in[2];
  const float* Wk = (const float*)d_in[3];
  const float* bk = (const float*)d_in[4];
  const float* Wv = (const float*)d_in[5];
  const float* bv = (const float*)d_in[6];
  const float* Wo = (const float*)d_in[7];
  const float* bo = (const float*)d_in[8];

  char* ws = (char*)d_ws;
  u16* Tb  = (u16*)(ws);               // T, later reused as attn output O
  u16* Wbf = (u16*)(ws + 16777216);
  u16* Qw  = (u16*)(ws + 18874368);
  u16* Kw  = (u16*)(ws + 35651584);
  u16* VTw = (u16*)(ws + 52428800);

  hipFuncSetAttribute((const void*)attn_kernel, hipFuncAttributeMaxDynamicSharedMemorySize, 135680);

  conv_w_kernel<<<512,256,0,stream>>>(Wq,Wk,Wv,Wo,Wbf);
  transpose_kernel<<<dim3(64,8,4),256,0,stream>>>(x, Tb);
  proj_kernel<0><<<dim3(32,4,12),256,0,stream>>>(Tb, Wbf, bq,bk,bv, Qw,Kw,VTw,nullptr);
  attn_kernel<<<dim3(256),512,135680,stream>>>(Qw,Kw,VTw,Tb);
  proj_kernel<1><<<dim3(32,4,4),256,0,stream>>>(Tb, Wbf, bo,nullptr,nullptr, nullptr,nullptr,nullptr,(float*)d_out);
}